// Round 5
// baseline (541.905 us; speedup 1.0000x reference)
//
#include <hip/hip_runtime.h>

// ---------------------------------------------------------------------------
// NeuralCellularAutomata fused pipeline for MI355X (gfx950) — v9
//   state[128,64,40,40] -> sobel perception(192) -> w1 GEMM(512) -> LN(sample)
//   -> ReLU -> w2 GEMM(64) -> mask*alive gate -> residual add
// v9 (post-mortem of v8: k2 still spilled — acc[6][6] needs ~230 live regs,
// no launch_bounds value fits that AND >=3 blk/CU. Algorithmic fix: fi-outer
// contraction — only acc[6] (24 regs) live at a time, contract each fi-row
// with G immediately. ~90 VGPR -> lb(256,4), 4 blk/CU, zero spill. Same math,
// 2.6x more LDS reads (LDS has 4x headroom vs MFMA in this kernel).
// k4 unchanged from v8 (v5 structure + HW f2bf + hoisted swizzle addressing).
// ---------------------------------------------------------------------------

typedef unsigned short u16;
typedef unsigned int   u32;
typedef __attribute__((ext_vector_type(8))) u16    ushort8;
typedef __attribute__((ext_vector_type(4))) u16    u16x4;
typedef __attribute__((ext_vector_type(8))) __bf16 bf16x8;
typedef __attribute__((ext_vector_type(4))) float  f32x4;
typedef __attribute__((ext_vector_type(4))) u32    u32x4;

#define NB   128
#define NC   64
#define K1   192
#define NO   512
#define NHW  1600
#define LN_N 819200.0f

__device__ __forceinline__ u16 f2bf(float f) {
    // HW round-nearest-even convert; compiler packs pairs into v_cvt_pk_bf16_f32
    union { __bf16 h; u16 u; } v; v.h = (__bf16)f; return v.u;
}
__device__ __forceinline__ float bf2f(u16 h) {
    union { u32 u; float f; } v; v.u = ((u32)h) << 16; return v.f;
}
__device__ __forceinline__ float bfhi(u32 c) {   // float from high bf16
    union { u32 u; float f; } v; v.u = c & 0xffff0000u; return v.f;
}
__device__ __forceinline__ float bflo(u32 c) {   // float from low bf16
    union { u32 u; float f; } v; v.u = c << 16; return v.f;
}
__device__ __forceinline__ f32x4 mfma16(bf16x8 a, bf16x8 b, f32x4 c) {
    return __builtin_amdgcn_mfma_f32_16x16x32_bf16(a, b, c, 0, 0, 0);
}
__device__ __forceinline__ bf16x8 ldfrag(const u16* p) {
    return *(const bf16x8*)p;
}

// Shared perception helpers so k2_stats and k4_fused produce IDENTICAL bf16 P.
__device__ __forceinline__ void load_halo(const float* __restrict__ base, int h,
                                          int wq, float reg[3][12]) {
#pragma unroll
    for (int jj = 0; jj < 3; ++jj) {
        int hh = h + jj - 1;
        bool vh = (unsigned)hh < 40u;
        const float* rowp = base + hh * 40;
#pragma unroll
        for (int i = 0; i < 12; ++i) {
            int col = wq * 10 - 1 + i;
            reg[jj][i] = (vh && (unsigned)col < 40u) ? rowp[col] : 0.0f;
        }
    }
}
__device__ __forceinline__ void sobel_px(const float reg[3][12], int t,
                                         float& sx, float& sy, float& idn) {
    sx = (reg[0][t + 2] - reg[0][t]) + 2.0f * (reg[1][t + 2] - reg[1][t])
       + (reg[2][t + 2] - reg[2][t]);
    sy = (reg[2][t] + 2.0f * reg[2][t + 1] + reg[2][t + 2])
       - (reg[0][t] + 2.0f * reg[0][t + 1] + reg[0][t + 2]);
    idn = reg[1][t + 1];
}

// --- k0a: pack w1 -> panel layout w1p + transposed w1T; w2 -> panel w2p -----
__global__ __launch_bounds__(256) void k0_convert(const float* __restrict__ w1,
                                                  const float* __restrict__ w2,
                                                  u16* __restrict__ w1p,
                                                  u16* __restrict__ w1T,
                                                  u16* __restrict__ w2p,
                                                  float* __restrict__ stats) {
    int g = blockIdx.x * 256 + threadIdx.x;
    if (g < NO * K1) {
        u16 v = f2bf(w1[g]);
        int o = g / K1, k = g - o * K1;
        int f = o >> 4, ks = k >> 5;
        int lane = (((k >> 3) & 3) << 4) | (o & 15);
        w1p[(size_t)(((f * 6 + ks) * 64 + lane) * 8 + (k & 7))] = v;
        w1T[(size_t)k * NO + o] = v;
    } else if (g < NO * K1 + NC * NO) {
        int i = g - NO * K1;
        int s = i / NO, o = i - s * NO;
        u16 v = f2bf(w2[i]);
        int wid = s >> 4, oc = o >> 6, ks2 = (o >> 5) & 1;
        int lane = (((o >> 3) & 3) << 4) | (s & 15);
        w2p[(size_t)((((wid * 8 + oc) * 2 + ks2) * 64 + lane) * 8 + (o & 7))] = v;
    } else if (g < NO * K1 + NC * NO + 256) {
        stats[g - NO * K1 - NC * NO] = 0.0f;
    }
}

// --- k0l: pack ln params into C-fragment panel order (coalesced reads) ------
__global__ __launch_bounds__(256) void k0_lncomb(const float* __restrict__ lnw,
                                                 const float* __restrict__ lnb,
                                                 u32* __restrict__ lnp) {
    int g = blockIdx.x * 256 + threadIdx.x;   // g = o*1600 + p
    int o = g / NHW, p = g - o * NHW;
    int bx = p / 80, pr = p - bx * 80;
    int mi = pr >> 4, l15 = pr & 15;
    int oc = o >> 6, ro = o & 63;
    int wid = ro >> 4, hi = (ro >> 2) & 3, r = ro & 3;
    int lane = (hi << 4) | l15;
    int outi = ((((bx * 8 + oc) * 4 + wid) * 5 + mi) << 8) + lane * 4 + r;
    lnp[outi] = ((u32)f2bf(lnb[g]) << 16) | f2bf(lnw[g]);
}

// --- k0g: G = w1^T w1 via MFMA (blocks 0..35); colw1 (block 36) -------------
__global__ __launch_bounds__(256) void k0_gram(const u16* __restrict__ w1T,
                                               float* __restrict__ G,
                                               float* __restrict__ colw1) {
    const int blk = blockIdx.x;
    const int tid = threadIdx.x;
    const int lane = tid & 63, wid = tid >> 6;
    const int q = lane >> 4, l15 = lane & 15;
    if (blk < 36) {
        int bj = blk / 6, bk = blk - bj * 6;
        int j0 = bj * 32 + (wid & 1) * 16, k0 = bk * 32 + (wid >> 1) * 16;
        f32x4 acc = {0.f, 0.f, 0.f, 0.f};
#pragma unroll
        for (int ks = 0; ks < 16; ++ks) {
            bf16x8 a  = ldfrag(&w1T[(size_t)(j0 + l15) * NO + ks * 32 + q * 8]);
            bf16x8 bb = ldfrag(&w1T[(size_t)(k0 + l15) * NO + ks * 32 + q * 8]);
            acc = mfma16(a, bb, acc);
        }
#pragma unroll
        for (int r = 0; r < 4; ++r)
            G[(size_t)(j0 + q * 4 + r) * K1 + k0 + l15] = acc[r];
    } else if (tid < K1) {
        float s = 0.f;
        for (int i = 0; i < NO / 8; ++i) {
            ushort8 v = *(const ushort8*)&w1T[(size_t)tid * NO + i * 8];
#pragma unroll
            for (int j = 0; j < 8; ++j) s += bf2f(v[j]);
        }
        colw1[tid] = s;
    }
}

// --- k2: per-sample LN stats via Gram MFMA — strip-parallel, fi-outer -------
// One block per (sample b, 2-row strip bx) = 2560 blocks. Pt[193][104]:
// rows 0..191 = P (k-channel major), row 192 = ones. LDS 40144 B.
// v9: fi-outer contraction — only acc[6] (24 regs) live; each fi-row of
// P'P tiles is contracted with G immediately after its 3-step ks loop.
// ~90 VGPR -> lb(256,4), 4 blocks/CU, no spill (v7/v8 spilled 0.8-1.6 GB).
__global__ __launch_bounds__(256, 4) void k2_stats(const float* __restrict__ state,
                                                   const float* __restrict__ G,
                                                   const float* __restrict__ colw1,
                                                   float* __restrict__ stats) {
    const int bx = blockIdx.x;                    // 0..19 strip
    const int b  = blockIdx.y;
    const int h0 = bx * 2;
    const int tid = threadIdx.x;
    const int lane = tid & 63, wid = tid >> 6;
    const int q = lane >> 4, l15 = lane & 15;
    const int j0 = (wid & 1) * 96, j1 = (wid >> 1) * 96, jo = wid * 48;

    __shared__ __align__(16) u16 Pt[193 * 104];   // 40144 B
    __shared__ float red[8];

    for (int i = tid; i < 193 * 104 / 8; i += 256) ((u32x4*)Pt)[i] = (u32x4){0,0,0,0};
    __syncthreads();
    if (tid < 80) Pt[192 * 104 + tid] = 0x3F80u;  // ones row (bf16 1.0)

    // perception: 2 rows, identical code to k4 (bitwise-identical bf16 P)
    {
        const int c = tid >> 2, wq = tid & 3;
        const float* base = state + ((size_t)b * NC + c) * NHW;
        for (int rr = 0; rr < 2; ++rr) {
            float reg[3][12];
            load_halo(base, h0 + rr, wq, reg);
#pragma unroll
            for (int t = 0; t < 10; ++t) {
                float sx, sy, idn; sobel_px(reg, t, sx, sy, idn);
                int px = rr * 40 + wq * 10 + t;
                Pt[(3 * c + 0) * 104 + px] = f2bf(sx);
                Pt[(3 * c + 1) * 104 + px] = f2bf(sy);
                Pt[(3 * c + 2) * 104 + px] = f2bf(idn);
            }
        }
    }
    __syncthreads();

    float ssq = 0.f;
#pragma unroll
    for (int fi = 0; fi < 6; ++fi) {
        f32x4 acc[6];
#pragma unroll
        for (int j = 0; j < 6; ++j) { f32x4 z = {0.f,0.f,0.f,0.f}; acc[j] = z; }
#pragma unroll
        for (int ks = 0; ks < 3; ++ks) {
            bf16x8 av = ldfrag(&Pt[(j0 + fi * 16 + l15) * 104 + ks * 32 + q * 8]);
#pragma unroll
            for (int fj = 0; fj < 6; ++fj) {
                bf16x8 bv = ldfrag(&Pt[(j1 + fj * 16 + l15) * 104 + ks * 32 + q * 8]);
                acc[fj] = mfma16(av, bv, acc[fj]);
            }
        }
#pragma unroll
        for (int fj = 0; fj < 6; ++fj) {
            f32x4 gv = *(const f32x4*)&G[(size_t)(j1 + fj * 16 + l15) * K1
                                         + j0 + fi * 16 + q * 4];
#pragma unroll
            for (int r = 0; r < 4; ++r) ssq += acc[fj][r] * gv[r];
        }
    }

    // ones-row pass: colsums of wid's 48-col slice (every D-row = colsum)
    f32x4 accO[3];
#pragma unroll
    for (int j = 0; j < 3; ++j) { f32x4 z = {0.f,0.f,0.f,0.f}; accO[j] = z; }
#pragma unroll
    for (int ks = 0; ks < 3; ++ks) {
        bf16x8 ao = ldfrag(&Pt[192 * 104 + ks * 32 + q * 8]);   // broadcast row
#pragma unroll
        for (int fj = 0; fj < 3; ++fj) {
            bf16x8 bo = ldfrag(&Pt[(jo + fj * 16 + l15) * 104 + ks * 32 + q * 8]);
            accO[fj] = mfma16(ao, bo, accO[fj]);
        }
    }
    float sm = 0.f;
    if (q == 0) {
#pragma unroll
        for (int fj = 0; fj < 3; ++fj)
            sm += accO[fj][0] * colw1[jo + fj * 16 + l15];
    }

#pragma unroll
    for (int off = 32; off > 0; off >>= 1) {
        ssq += __shfl_down(ssq, off);
        sm  += __shfl_down(sm, off);
    }
    if (lane == 0) { red[wid] = ssq; red[4 + wid] = sm; }
    __syncthreads();
    if (tid == 0) {
        atomicAdd(&stats[b * 2],     red[4] + red[5] + red[6] + red[7]);
        atomicAdd(&stats[b * 2 + 1], red[0] + red[1] + red[2] + red[3]);
    }
}

// --- k3: finalize per-sample mu / rsigma ------------------------------------
__global__ void k3_finalize(const float* __restrict__ stats, float2* __restrict__ musig) {
    int t = threadIdx.x;
    if (t < NB) {
        float s = stats[2 * t], qq = stats[2 * t + 1];
        float inv = 1.0f / LN_N;
        float mu = s * inv;
        float var = qq * inv - mu * mu;
        float2 r; r.x = mu; r.y = rsqrtf(var + 1e-5f);
        musig[t] = r;
    }
}

// --- k4: fused percept -> GEMM1 -> LN/ReLU -> GEMM2 -> gate+residual --------
// v5 structure (single Ys, 2 barriers/oc, LDS 40960, lb(256,4)) with
// HW f2bf cvt + hoisted block-constant LDS swizzle addressing.
__global__ __launch_bounds__(256, 4) void k4_fused(const float* __restrict__ state,
                                                   const u16* __restrict__ w1p,
                                                   const u16* __restrict__ w2p,
                                                   const u32* __restrict__ lnp,
                                                   const int* __restrict__ mask,
                                                   const float2* __restrict__ musig,
                                                   float* __restrict__ out) {
    const int bx = blockIdx.x;                    // 0..19
    const int b  = blockIdx.y;
    const int p0 = bx * 80, h0 = bx * 2;
    const int tid = threadIdx.x;
    const int lane = tid & 63, wid = tid >> 6;
    const int q = lane >> 4, l15 = lane & 15;

    __shared__ __align__(16) u16 Pt[80 * 192];    // 30720 B
    __shared__ __align__(16) u16 Ys[80 * 64];     // 10240 B [p][o-chunk] swizzled

    const float2 ms = musig[b];
    const float mu = ms.x, rs = ms.y;
    const float murs = mu * rs;

    // perception -> Pt [p][192], group-of-8 XOR swizzle on 16B units
    {
        const int c = tid >> 2, wq = tid & 3;
        const float* base = state + ((size_t)b * NC + c) * NHW;
        for (int rr = 0; rr < 2; ++rr) {
            float reg[3][12];
            load_halo(base, h0 + rr, wq, reg);
#pragma unroll
            for (int t = 0; t < 10; ++t) {
                float sx, sy, idn; sobel_px(reg, t, sx, sy, idn);
                int px = rr * 40 + wq * 10 + t;
                int k = 3 * c;
#pragma unroll
                for (int i = 0; i < 3; ++i) {
                    int kk = k + i, u = kk >> 3;
                    int elem = px * 192 + (((u & 0x18) | ((u ^ px) & 7)) << 3) + (kk & 7);
                    Pt[elem] = f2bf(i == 0 ? sx : (i == 1 ? sy : idn));
                }
            }
        }
    }
    // gate in VGPRs: g5[mi] for p = p0 + mi*16 + l15
    float g5[5];
    {
        const float* st3 = state + ((size_t)b * NC + 3) * NHW;
#pragma unroll
        for (int mi = 0; mi < 5; ++mi) {
            int p = p0 + mi * 16 + l15;
            int h = p / 40, w = p - h * 40;
            float mx = -1e30f;
#pragma unroll
            for (int dh = -1; dh <= 1; ++dh) {
                int hh = h + dh;
                if ((unsigned)hh < 40u)
#pragma unroll
                    for (int dw = -1; dw <= 1; ++dw) {
                        int wc = w + dw;
                        if ((unsigned)wc < 40u) mx = fmaxf(mx, st3[hh * 40 + wc]);
                    }
            }
            g5[mi] = (mx > 0.1f && mask[p] != 0) ? 1.0f : 0.0f;
        }
    }

    // ---- block-constant LDS addressing (hoisted out of the oc loop) --------
    int pB0[5], pB1[5], yR0[5], yR1[5], yW[5];
    {
        const int q8 = q << 3;
        const int wu = wid * 2 + (q >> 1);
#pragma unroll
        for (int mi = 0; mi < 5; ++mi) {
            int r  = mi * 16 + l15;
            int xr = (r & 7) << 3;
            pB0[mi] = r * 192 + (q8 ^ xr);
            pB1[mi] = r * 192 + ((q8 + 32) ^ xr);
            int px = r & 7;
            yR0[mi] = r * 64 + ((q ^ px) << 3);
            yR1[mi] = r * 64 + (((q + 4) ^ px) << 3);
            yW[mi]  = r * 64 + ((wu ^ px) << 3) + (q & 1) * 4;
        }
    }
    __syncthreads();

    f32x4 acc2[5];
#pragma unroll
    for (int i = 0; i < 5; ++i) { f32x4 z = {0.f,0.f,0.f,0.f}; acc2[i] = z; }

    for (int oc = 0; oc < 8; ++oc) {
        // prefetch ln C-fragments (panel layout: lane*16B, coalesced)
        u32x4 lv[5];
        {
            const u32* lb = lnp + ((((size_t)bx * 8 + oc) * 4 + wid) * 5) * 256 + lane * 4;
#pragma unroll
            for (int mi = 0; mi < 5; ++mi)
                lv[mi] = *(const u32x4*)(lb + mi * 256);
        }
        // prefetch w2 A-frags for this chunk (panel layout, coalesced)
        const u16* w2base = w2p + ((size_t)(wid * 8 + oc) * 2) * 512 + lane * 8;
        bf16x8 aw0 = ldfrag(w2base);
        bf16x8 aw1 = ldfrag(w2base + 512);

        // ---- GEMM1: D[o][p], wave o-tile 16 ----
        f32x4 acc1[5];
#pragma unroll
        for (int i = 0; i < 5; ++i) { f32x4 z = {0.f,0.f,0.f,0.f}; acc1[i] = z; }
        const u16* w1base = w1p + ((size_t)(oc * 4 + wid) * 6) * 512 + lane * 8;
#pragma unroll
        for (int ks = 0; ks < 6; ++ks) {
            bf16x8 a = ldfrag(w1base + ks * 512);
#pragma unroll
            for (int mi = 0; mi < 5; ++mi) {
                int off = ((ks & 1) ? pB1[mi] : pB0[mi]) + (ks >> 1) * 64;
                acc1[mi] = mfma16(a, ldfrag(&Pt[off]), acc1[mi]);
            }
        }
        // ---- transform: Y = relu((x-mu)*rs*lnw + lnb) -> Ys (b64 swizzled) ----
#pragma unroll
        for (int mi = 0; mi < 5; ++mi) {
            u16x4 yv;
#pragma unroll
            for (int r = 0; r < 4; ++r) {
                u32 cc = lv[mi][r];
                float t = fmaf(acc1[mi][r], rs, -murs);
                float y = fmaxf(fmaf(t, bflo(cc), bfhi(cc)), 0.0f);
                yv[r] = f2bf(y);
            }
            *(u16x4*)&Ys[yW[mi]] = yv;
        }
        __syncthreads();
        // ---- GEMM2 partial: D[s][p] += w2[s][o64] * Ys[o64][p] ----
#pragma unroll
        for (int ks2 = 0; ks2 < 2; ++ks2) {
            bf16x8 aw = ks2 ? aw1 : aw0;
#pragma unroll
            for (int mi = 0; mi < 5; ++mi) {
                int off = ks2 ? yR1[mi] : yR0[mi];
                acc2[mi] = mfma16(aw, ldfrag(&Ys[off]), acc2[mi]);
            }
        }
        __syncthreads();                          // Ys reads done before rewrite
    }

    // ---- epilogue: direct gated residual stores ----
#pragma unroll
    for (int mi = 0; mi < 5; ++mi) {
        int p = p0 + mi * 16 + l15;
        float g = g5[mi];
#pragma unroll
        for (int r = 0; r < 4; ++r) {
            int s = wid * 16 + q * 4 + r;
            size_t idx = ((size_t)b * NC + s) * NHW + p;
            out[idx] = state[idx] + g * acc2[mi][r];
        }
    }
}

// ---------------------------------------------------------------------------
extern "C" void kernel_launch(void* const* d_in, const int* in_sizes, int n_in,
                              void* d_out, int out_size, void* d_ws, size_t ws_size,
                              hipStream_t stream) {
    const float* state = (const float*)d_in[0];
    const float* w1    = (const float*)d_in[1];
    const float* lnw   = (const float*)d_in[2];
    const float* lnb   = (const float*)d_in[3];
    const float* w2    = (const float*)d_in[4];
    const int*   mask  = (const int*)d_in[5];
    float* out = (float*)d_out;

    char* ws = (char*)d_ws;
    // workspace layout (total ~3.89 MB):
    u16*    w1p   = (u16*)(ws + 0ull);          //   196,608  panel layout
    u16*    w2p   = (u16*)(ws + 196608ull);     //    65,536  panel layout
    u32*    lnp   = (u32*)(ws + 262144ull);     // 3,276,800  panel (lnb|lnw)
    u16*    w1T   = (u16*)(ws + 3538944ull);    //   196,608  [k][o]
    float*  G     = (float*)(ws + 3735552ull);  //   147,456  w1^T w1
    float*  colw1 = (float*)(ws + 3883008ull);  //       768
    float*  stats = (float*)(ws + 3883776ull);  //     1,024  (sum,sumsq)*128
    float2* musig = (float2*)(ws + 3884800ull); //     1,024

    k0_convert <<<513, 256, 0, stream>>>(w1, w2, w1p, w1T, w2p, stats);
    k0_lncomb  <<<3200, 256, 0, stream>>>(lnw, lnb, lnp);
    k0_gram    <<<37, 256, 0, stream>>>(w1T, G, colw1);
    k2_stats   <<<dim3(20, 128), 256, 0, stream>>>(state, G, colw1, stats);
    k3_finalize<<<1, 128, 0, stream>>>(stats, musig);
    k4_fused   <<<dim3(20, 128), 256, 0, stream>>>(state, w1p, w2p, lnp,
                                                   mask, musig, out);
}

// Round 6
// 313.178 us; speedup vs baseline: 1.7303x; 1.7303x over previous
//
#include <hip/hip_runtime.h>

// ---------------------------------------------------------------------------
// NeuralCellularAutomata fused pipeline for MI355X (gfx950) — v10
//   state[128,64,40,40] -> sobel perception(192) -> w1 GEMM(512) -> LN(sample)
//   -> ReLU -> w2 GEMM(64) -> mask*alive gate -> residual add
// v10 (post-mortem of v9: VGPR_Count=64 under lb(256,4) revealed the unified
// register file splits the launch_bounds budget ~evenly between arch VGPRs
// and AGPRs (128 -> 64+64, 170 -> 84+84). Every min-waves-bounded k2 spilled;
// v5's unbounded k2 never did. Fix: k2 uses plain __launch_bounds__(256) —
// no cap, no spill; occupancy is LDS-capped at 3-4 blk/CU regardless.
// #pragma unroll 1 on the fi loop keeps per-fi live sets from merging.)
// k4 unchanged (v5 structure + HW f2bf + hoisted swizzle addressing).
// ---------------------------------------------------------------------------

typedef unsigned short u16;
typedef unsigned int   u32;
typedef __attribute__((ext_vector_type(8))) u16    ushort8;
typedef __attribute__((ext_vector_type(4))) u16    u16x4;
typedef __attribute__((ext_vector_type(8))) __bf16 bf16x8;
typedef __attribute__((ext_vector_type(4))) float  f32x4;
typedef __attribute__((ext_vector_type(4))) u32    u32x4;

#define NB   128
#define NC   64
#define K1   192
#define NO   512
#define NHW  1600
#define LN_N 819200.0f

__device__ __forceinline__ u16 f2bf(float f) {
    // HW round-nearest-even convert; compiler packs pairs into v_cvt_pk_bf16_f32
    union { __bf16 h; u16 u; } v; v.h = (__bf16)f; return v.u;
}
__device__ __forceinline__ float bf2f(u16 h) {
    union { u32 u; float f; } v; v.u = ((u32)h) << 16; return v.f;
}
__device__ __forceinline__ float bfhi(u32 c) {   // float from high bf16
    union { u32 u; float f; } v; v.u = c & 0xffff0000u; return v.f;
}
__device__ __forceinline__ float bflo(u32 c) {   // float from low bf16
    union { u32 u; float f; } v; v.u = c << 16; return v.f;
}
__device__ __forceinline__ f32x4 mfma16(bf16x8 a, bf16x8 b, f32x4 c) {
    return __builtin_amdgcn_mfma_f32_16x16x32_bf16(a, b, c, 0, 0, 0);
}
__device__ __forceinline__ bf16x8 ldfrag(const u16* p) {
    return *(const bf16x8*)p;
}

// Shared perception helpers so k2_stats and k4_fused produce IDENTICAL bf16 P.
__device__ __forceinline__ void load_halo(const float* __restrict__ base, int h,
                                          int wq, float reg[3][12]) {
#pragma unroll
    for (int jj = 0; jj < 3; ++jj) {
        int hh = h + jj - 1;
        bool vh = (unsigned)hh < 40u;
        const float* rowp = base + hh * 40;
#pragma unroll
        for (int i = 0; i < 12; ++i) {
            int col = wq * 10 - 1 + i;
            reg[jj][i] = (vh && (unsigned)col < 40u) ? rowp[col] : 0.0f;
        }
    }
}
__device__ __forceinline__ void sobel_px(const float reg[3][12], int t,
                                         float& sx, float& sy, float& idn) {
    sx = (reg[0][t + 2] - reg[0][t]) + 2.0f * (reg[1][t + 2] - reg[1][t])
       + (reg[2][t + 2] - reg[2][t]);
    sy = (reg[2][t] + 2.0f * reg[2][t + 1] + reg[2][t + 2])
       - (reg[0][t] + 2.0f * reg[0][t + 1] + reg[0][t + 2]);
    idn = reg[1][t + 1];
}

// --- k0a: pack w1 -> panel layout w1p + transposed w1T; w2 -> panel w2p -----
__global__ __launch_bounds__(256) void k0_convert(const float* __restrict__ w1,
                                                  const float* __restrict__ w2,
                                                  u16* __restrict__ w1p,
                                                  u16* __restrict__ w1T,
                                                  u16* __restrict__ w2p,
                                                  float* __restrict__ stats) {
    int g = blockIdx.x * 256 + threadIdx.x;
    if (g < NO * K1) {
        u16 v = f2bf(w1[g]);
        int o = g / K1, k = g - o * K1;
        int f = o >> 4, ks = k >> 5;
        int lane = (((k >> 3) & 3) << 4) | (o & 15);
        w1p[(size_t)(((f * 6 + ks) * 64 + lane) * 8 + (k & 7))] = v;
        w1T[(size_t)k * NO + o] = v;
    } else if (g < NO * K1 + NC * NO) {
        int i = g - NO * K1;
        int s = i / NO, o = i - s * NO;
        u16 v = f2bf(w2[i]);
        int wid = s >> 4, oc = o >> 6, ks2 = (o >> 5) & 1;
        int lane = (((o >> 3) & 3) << 4) | (s & 15);
        w2p[(size_t)((((wid * 8 + oc) * 2 + ks2) * 64 + lane) * 8 + (o & 7))] = v;
    } else if (g < NO * K1 + NC * NO + 256) {
        stats[g - NO * K1 - NC * NO] = 0.0f;
    }
}

// --- k0l: pack ln params into C-fragment panel order (coalesced reads) ------
__global__ __launch_bounds__(256) void k0_lncomb(const float* __restrict__ lnw,
                                                 const float* __restrict__ lnb,
                                                 u32* __restrict__ lnp) {
    int g = blockIdx.x * 256 + threadIdx.x;   // g = o*1600 + p
    int o = g / NHW, p = g - o * NHW;
    int bx = p / 80, pr = p - bx * 80;
    int mi = pr >> 4, l15 = pr & 15;
    int oc = o >> 6, ro = o & 63;
    int wid = ro >> 4, hi = (ro >> 2) & 3, r = ro & 3;
    int lane = (hi << 4) | l15;
    int outi = ((((bx * 8 + oc) * 4 + wid) * 5 + mi) << 8) + lane * 4 + r;
    lnp[outi] = ((u32)f2bf(lnb[g]) << 16) | f2bf(lnw[g]);
}

// --- k0g: G = w1^T w1 via MFMA (blocks 0..35); colw1 (block 36) -------------
__global__ __launch_bounds__(256) void k0_gram(const u16* __restrict__ w1T,
                                               float* __restrict__ G,
                                               float* __restrict__ colw1) {
    const int blk = blockIdx.x;
    const int tid = threadIdx.x;
    const int lane = tid & 63, wid = tid >> 6;
    const int q = lane >> 4, l15 = lane & 15;
    if (blk < 36) {
        int bj = blk / 6, bk = blk - bj * 6;
        int j0 = bj * 32 + (wid & 1) * 16, k0 = bk * 32 + (wid >> 1) * 16;
        f32x4 acc = {0.f, 0.f, 0.f, 0.f};
#pragma unroll
        for (int ks = 0; ks < 16; ++ks) {
            bf16x8 a  = ldfrag(&w1T[(size_t)(j0 + l15) * NO + ks * 32 + q * 8]);
            bf16x8 bb = ldfrag(&w1T[(size_t)(k0 + l15) * NO + ks * 32 + q * 8]);
            acc = mfma16(a, bb, acc);
        }
#pragma unroll
        for (int r = 0; r < 4; ++r)
            G[(size_t)(j0 + q * 4 + r) * K1 + k0 + l15] = acc[r];
    } else if (tid < K1) {
        float s = 0.f;
        for (int i = 0; i < NO / 8; ++i) {
            ushort8 v = *(const ushort8*)&w1T[(size_t)tid * NO + i * 8];
#pragma unroll
            for (int j = 0; j < 8; ++j) s += bf2f(v[j]);
        }
        colw1[tid] = s;
    }
}

// --- k2: per-sample LN stats via Gram MFMA — strip-parallel, fi-outer -------
// One block per (sample b, 2-row strip bx) = 2560 blocks. Pt[193][104]:
// rows 0..191 = P (k-channel major), row 192 = ones. LDS 40144 B.
// fi-outer contraction: only acc[6] live per fi; contracted with G
// immediately. v10: NO min-waves launch bound — the unified VGPR/AGPR file
// splits a bounded budget ~evenly (128 -> 64+64 arch/acc) which starved the
// arch side and spilled 0.75-1.6 GB in v7/v8/v9. Unbounded = no spill;
// occupancy is LDS-capped (3-4 blk/CU) regardless.
__global__ __launch_bounds__(256) void k2_stats(const float* __restrict__ state,
                                                const float* __restrict__ G,
                                                const float* __restrict__ colw1,
                                                float* __restrict__ stats) {
    const int bx = blockIdx.x;                    // 0..19 strip
    const int b  = blockIdx.y;
    const int h0 = bx * 2;
    const int tid = threadIdx.x;
    const int lane = tid & 63, wid = tid >> 6;
    const int q = lane >> 4, l15 = lane & 15;
    const int j0 = (wid & 1) * 96, j1 = (wid >> 1) * 96, jo = wid * 48;

    __shared__ __align__(16) u16 Pt[193 * 104];   // 40144 B
    __shared__ float red[8];

    for (int i = tid; i < 193 * 104 / 8; i += 256) ((u32x4*)Pt)[i] = (u32x4){0,0,0,0};
    __syncthreads();
    if (tid < 80) Pt[192 * 104 + tid] = 0x3F80u;  // ones row (bf16 1.0)

    // perception: 2 rows, identical code to k4 (bitwise-identical bf16 P)
    {
        const int c = tid >> 2, wq = tid & 3;
        const float* base = state + ((size_t)b * NC + c) * NHW;
        for (int rr = 0; rr < 2; ++rr) {
            float reg[3][12];
            load_halo(base, h0 + rr, wq, reg);
#pragma unroll
            for (int t = 0; t < 10; ++t) {
                float sx, sy, idn; sobel_px(reg, t, sx, sy, idn);
                int px = rr * 40 + wq * 10 + t;
                Pt[(3 * c + 0) * 104 + px] = f2bf(sx);
                Pt[(3 * c + 1) * 104 + px] = f2bf(sy);
                Pt[(3 * c + 2) * 104 + px] = f2bf(idn);
            }
        }
    }
    __syncthreads();

    float ssq = 0.f;
#pragma unroll 1
    for (int fi = 0; fi < 6; ++fi) {
        f32x4 acc[6];
#pragma unroll
        for (int j = 0; j < 6; ++j) { f32x4 z = {0.f,0.f,0.f,0.f}; acc[j] = z; }
#pragma unroll
        for (int ks = 0; ks < 3; ++ks) {
            bf16x8 av = ldfrag(&Pt[(j0 + fi * 16 + l15) * 104 + ks * 32 + q * 8]);
#pragma unroll
            for (int fj = 0; fj < 6; ++fj) {
                bf16x8 bv = ldfrag(&Pt[(j1 + fj * 16 + l15) * 104 + ks * 32 + q * 8]);
                acc[fj] = mfma16(av, bv, acc[fj]);
            }
        }
#pragma unroll
        for (int fj = 0; fj < 6; ++fj) {
            f32x4 gv = *(const f32x4*)&G[(size_t)(j1 + fj * 16 + l15) * K1
                                         + j0 + fi * 16 + q * 4];
#pragma unroll
            for (int r = 0; r < 4; ++r) ssq += acc[fj][r] * gv[r];
        }
    }

    // ones-row pass: colsums of wid's 48-col slice (every D-row = colsum)
    f32x4 accO[3];
#pragma unroll
    for (int j = 0; j < 3; ++j) { f32x4 z = {0.f,0.f,0.f,0.f}; accO[j] = z; }
#pragma unroll
    for (int ks = 0; ks < 3; ++ks) {
        bf16x8 ao = ldfrag(&Pt[192 * 104 + ks * 32 + q * 8]);   // broadcast row
#pragma unroll
        for (int fj = 0; fj < 3; ++fj) {
            bf16x8 bo = ldfrag(&Pt[(jo + fj * 16 + l15) * 104 + ks * 32 + q * 8]);
            accO[fj] = mfma16(ao, bo, accO[fj]);
        }
    }
    float sm = 0.f;
    if (q == 0) {
#pragma unroll
        for (int fj = 0; fj < 3; ++fj)
            sm += accO[fj][0] * colw1[jo + fj * 16 + l15];
    }

#pragma unroll
    for (int off = 32; off > 0; off >>= 1) {
        ssq += __shfl_down(ssq, off);
        sm  += __shfl_down(sm, off);
    }
    if (lane == 0) { red[wid] = ssq; red[4 + wid] = sm; }
    __syncthreads();
    if (tid == 0) {
        atomicAdd(&stats[b * 2],     red[4] + red[5] + red[6] + red[7]);
        atomicAdd(&stats[b * 2 + 1], red[0] + red[1] + red[2] + red[3]);
    }
}

// --- k3: finalize per-sample mu / rsigma ------------------------------------
__global__ void k3_finalize(const float* __restrict__ stats, float2* __restrict__ musig) {
    int t = threadIdx.x;
    if (t < NB) {
        float s = stats[2 * t], qq = stats[2 * t + 1];
        float inv = 1.0f / LN_N;
        float mu = s * inv;
        float var = qq * inv - mu * mu;
        float2 r; r.x = mu; r.y = rsqrtf(var + 1e-5f);
        musig[t] = r;
    }
}

// --- k4: fused percept -> GEMM1 -> LN/ReLU -> GEMM2 -> gate+residual --------
// v5 structure (single Ys, 2 barriers/oc, LDS 40960, lb(256,4)) with
// HW f2bf cvt + hoisted block-constant LDS swizzle addressing.
__global__ __launch_bounds__(256, 4) void k4_fused(const float* __restrict__ state,
                                                   const u16* __restrict__ w1p,
                                                   const u16* __restrict__ w2p,
                                                   const u32* __restrict__ lnp,
                                                   const int* __restrict__ mask,
                                                   const float2* __restrict__ musig,
                                                   float* __restrict__ out) {
    const int bx = blockIdx.x;                    // 0..19
    const int b  = blockIdx.y;
    const int p0 = bx * 80, h0 = bx * 2;
    const int tid = threadIdx.x;
    const int lane = tid & 63, wid = tid >> 6;
    const int q = lane >> 4, l15 = lane & 15;

    __shared__ __align__(16) u16 Pt[80 * 192];    // 30720 B
    __shared__ __align__(16) u16 Ys[80 * 64];     // 10240 B [p][o-chunk] swizzled

    const float2 ms = musig[b];
    const float mu = ms.x, rs = ms.y;
    const float murs = mu * rs;

    // perception -> Pt [p][192], group-of-8 XOR swizzle on 16B units
    {
        const int c = tid >> 2, wq = tid & 3;
        const float* base = state + ((size_t)b * NC + c) * NHW;
        for (int rr = 0; rr < 2; ++rr) {
            float reg[3][12];
            load_halo(base, h0 + rr, wq, reg);
#pragma unroll
            for (int t = 0; t < 10; ++t) {
                float sx, sy, idn; sobel_px(reg, t, sx, sy, idn);
                int px = rr * 40 + wq * 10 + t;
                int k = 3 * c;
#pragma unroll
                for (int i = 0; i < 3; ++i) {
                    int kk = k + i, u = kk >> 3;
                    int elem = px * 192 + (((u & 0x18) | ((u ^ px) & 7)) << 3) + (kk & 7);
                    Pt[elem] = f2bf(i == 0 ? sx : (i == 1 ? sy : idn));
                }
            }
        }
    }
    // gate in VGPRs: g5[mi] for p = p0 + mi*16 + l15
    float g5[5];
    {
        const float* st3 = state + ((size_t)b * NC + 3) * NHW;
#pragma unroll
        for (int mi = 0; mi < 5; ++mi) {
            int p = p0 + mi * 16 + l15;
            int h = p / 40, w = p - h * 40;
            float mx = -1e30f;
#pragma unroll
            for (int dh = -1; dh <= 1; ++dh) {
                int hh = h + dh;
                if ((unsigned)hh < 40u)
#pragma unroll
                    for (int dw = -1; dw <= 1; ++dw) {
                        int wc = w + dw;
                        if ((unsigned)wc < 40u) mx = fmaxf(mx, st3[hh * 40 + wc]);
                    }
            }
            g5[mi] = (mx > 0.1f && mask[p] != 0) ? 1.0f : 0.0f;
        }
    }

    // ---- block-constant LDS addressing (hoisted out of the oc loop) --------
    int pB0[5], pB1[5], yR0[5], yR1[5], yW[5];
    {
        const int q8 = q << 3;
        const int wu = wid * 2 + (q >> 1);
#pragma unroll
        for (int mi = 0; mi < 5; ++mi) {
            int r  = mi * 16 + l15;
            int xr = (r & 7) << 3;
            pB0[mi] = r * 192 + (q8 ^ xr);
            pB1[mi] = r * 192 + ((q8 + 32) ^ xr);
            int px = r & 7;
            yR0[mi] = r * 64 + ((q ^ px) << 3);
            yR1[mi] = r * 64 + (((q + 4) ^ px) << 3);
            yW[mi]  = r * 64 + ((wu ^ px) << 3) + (q & 1) * 4;
        }
    }
    __syncthreads();

    f32x4 acc2[5];
#pragma unroll
    for (int i = 0; i < 5; ++i) { f32x4 z = {0.f,0.f,0.f,0.f}; acc2[i] = z; }

    for (int oc = 0; oc < 8; ++oc) {
        // prefetch ln C-fragments (panel layout: lane*16B, coalesced)
        u32x4 lv[5];
        {
            const u32* lb = lnp + ((((size_t)bx * 8 + oc) * 4 + wid) * 5) * 256 + lane * 4;
#pragma unroll
            for (int mi = 0; mi < 5; ++mi)
                lv[mi] = *(const u32x4*)(lb + mi * 256);
        }
        // prefetch w2 A-frags for this chunk (panel layout, coalesced)
        const u16* w2base = w2p + ((size_t)(wid * 8 + oc) * 2) * 512 + lane * 8;
        bf16x8 aw0 = ldfrag(w2base);
        bf16x8 aw1 = ldfrag(w2base + 512);

        // ---- GEMM1: D[o][p], wave o-tile 16 ----
        f32x4 acc1[5];
#pragma unroll
        for (int i = 0; i < 5; ++i) { f32x4 z = {0.f,0.f,0.f,0.f}; acc1[i] = z; }
        const u16* w1base = w1p + ((size_t)(oc * 4 + wid) * 6) * 512 + lane * 8;
#pragma unroll
        for (int ks = 0; ks < 6; ++ks) {
            bf16x8 a = ldfrag(w1base + ks * 512);
#pragma unroll
            for (int mi = 0; mi < 5; ++mi) {
                int off = ((ks & 1) ? pB1[mi] : pB0[mi]) + (ks >> 1) * 64;
                acc1[mi] = mfma16(a, ldfrag(&Pt[off]), acc1[mi]);
            }
        }
        // ---- transform: Y = relu((x-mu)*rs*lnw + lnb) -> Ys (b64 swizzled) ----
#pragma unroll
        for (int mi = 0; mi < 5; ++mi) {
            u16x4 yv;
#pragma unroll
            for (int r = 0; r < 4; ++r) {
                u32 cc = lv[mi][r];
                float t = fmaf(acc1[mi][r], rs, -murs);
                float y = fmaxf(fmaf(t, bflo(cc), bfhi(cc)), 0.0f);
                yv[r] = f2bf(y);
            }
            *(u16x4*)&Ys[yW[mi]] = yv;
        }
        __syncthreads();
        // ---- GEMM2 partial: D[s][p] += w2[s][o64] * Ys[o64][p] ----
#pragma unroll
        for (int ks2 = 0; ks2 < 2; ++ks2) {
            bf16x8 aw = ks2 ? aw1 : aw0;
#pragma unroll
            for (int mi = 0; mi < 5; ++mi) {
                int off = ks2 ? yR1[mi] : yR0[mi];
                acc2[mi] = mfma16(aw, ldfrag(&Ys[off]), acc2[mi]);
            }
        }
        __syncthreads();                          // Ys reads done before rewrite
    }

    // ---- epilogue: direct gated residual stores ----
#pragma unroll
    for (int mi = 0; mi < 5; ++mi) {
        int p = p0 + mi * 16 + l15;
        float g = g5[mi];
#pragma unroll
        for (int r = 0; r < 4; ++r) {
            int s = wid * 16 + q * 4 + r;
            size_t idx = ((size_t)b * NC + s) * NHW + p;
            out[idx] = state[idx] + g * acc2[mi][r];
        }
    }
}

// ---------------------------------------------------------------------------
extern "C" void kernel_launch(void* const* d_in, const int* in_sizes, int n_in,
                              void* d_out, int out_size, void* d_ws, size_t ws_size,
                              hipStream_t stream) {
    const float* state = (const float*)d_in[0];
    const float* w1    = (const float*)d_in[1];
    const float* lnw   = (const float*)d_in[2];
    const float* lnb   = (const float*)d_in[3];
    const float* w2    = (const float*)d_in[4];
    const int*   mask  = (const int*)d_in[5];
    float* out = (float*)d_out;

    char* ws = (char*)d_ws;
    // workspace layout (total ~3.89 MB):
    u16*    w1p   = (u16*)(ws + 0ull);          //   196,608  panel layout
    u16*    w2p   = (u16*)(ws + 196608ull);     //    65,536  panel layout
    u32*    lnp   = (u32*)(ws + 262144ull);     // 3,276,800  panel (lnb|lnw)
    u16*    w1T   = (u16*)(ws + 3538944ull);    //   196,608  [k][o]
    float*  G     = (float*)(ws + 3735552ull);  //   147,456  w1^T w1
    float*  colw1 = (float*)(ws + 3883008ull);  //       768
    float*  stats = (float*)(ws + 3883776ull);  //     1,024  (sum,sumsq)*128
    float2* musig = (float2*)(ws + 3884800ull); //     1,024

    k0_convert <<<513, 256, 0, stream>>>(w1, w2, w1p, w1T, w2p, stats);
    k0_lncomb  <<<3200, 256, 0, stream>>>(lnw, lnb, lnp);
    k0_gram    <<<37, 256, 0, stream>>>(w1T, G, colw1);
    k2_stats   <<<dim3(20, 128), 256, 0, stream>>>(state, G, colw1, stats);
    k3_finalize<<<1, 128, 0, stream>>>(stats, musig);
    k4_fused   <<<dim3(20, 128), 256, 0, stream>>>(state, w1p, w2p, lnp,
                                                   mask, musig, out);
}

// Round 7
// 292.946 us; speedup vs baseline: 1.8498x; 1.0691x over previous
//
#include <hip/hip_runtime.h>

// ---------------------------------------------------------------------------
// NeuralCellularAutomata fused pipeline for MI355X (gfx950) — v11
//   state[128,64,40,40] -> sobel perception(192) -> w1 GEMM(512) -> LN(sample)
//   -> ReLU -> w2 GEMM(64) -> mask*alive gate -> residual add
// v11 (v10 confirmed k2 spill fixed; k4 back on top at 139us, MfmaUtil 16 /
// VALUBusy 32 / ~50% stall):
//   k4: (1) w1 A-frag software pipeline depth-1 — each oc's 6 global loads
//       were a lockstep post-barrier stall 8x/block; now prefetched during
//       the previous oc's MFMA chain. (2) lb(256,3): occupancy is LDS-capped
//       at 3 blk/CU anyway; 170-reg cap gives the prefetch headroom without
//       spill (v10's 128 cap was at 104 used). (3) k3 folded into k4
//       prologue (reads stats[] directly) — one fewer launch.
//   k2/k0*: frozen from v10 for clean attribution.
// ---------------------------------------------------------------------------

typedef unsigned short u16;
typedef unsigned int   u32;
typedef __attribute__((ext_vector_type(8))) u16    ushort8;
typedef __attribute__((ext_vector_type(4))) u16    u16x4;
typedef __attribute__((ext_vector_type(8))) __bf16 bf16x8;
typedef __attribute__((ext_vector_type(4))) float  f32x4;
typedef __attribute__((ext_vector_type(4))) u32    u32x4;

#define NB   128
#define NC   64
#define K1   192
#define NO   512
#define NHW  1600
#define LN_N 819200.0f

__device__ __forceinline__ u16 f2bf(float f) {
    // HW round-nearest-even convert; compiler packs pairs into v_cvt_pk_bf16_f32
    union { __bf16 h; u16 u; } v; v.h = (__bf16)f; return v.u;
}
__device__ __forceinline__ float bf2f(u16 h) {
    union { u32 u; float f; } v; v.u = ((u32)h) << 16; return v.f;
}
__device__ __forceinline__ float bfhi(u32 c) {   // float from high bf16
    union { u32 u; float f; } v; v.u = c & 0xffff0000u; return v.f;
}
__device__ __forceinline__ float bflo(u32 c) {   // float from low bf16
    union { u32 u; float f; } v; v.u = c << 16; return v.f;
}
__device__ __forceinline__ f32x4 mfma16(bf16x8 a, bf16x8 b, f32x4 c) {
    return __builtin_amdgcn_mfma_f32_16x16x32_bf16(a, b, c, 0, 0, 0);
}
__device__ __forceinline__ bf16x8 ldfrag(const u16* p) {
    return *(const bf16x8*)p;
}

// Shared perception helpers so k2_stats and k4_fused produce IDENTICAL bf16 P.
__device__ __forceinline__ void load_halo(const float* __restrict__ base, int h,
                                          int wq, float reg[3][12]) {
#pragma unroll
    for (int jj = 0; jj < 3; ++jj) {
        int hh = h + jj - 1;
        bool vh = (unsigned)hh < 40u;
        const float* rowp = base + hh * 40;
#pragma unroll
        for (int i = 0; i < 12; ++i) {
            int col = wq * 10 - 1 + i;
            reg[jj][i] = (vh && (unsigned)col < 40u) ? rowp[col] : 0.0f;
        }
    }
}
__device__ __forceinline__ void sobel_px(const float reg[3][12], int t,
                                         float& sx, float& sy, float& idn) {
    sx = (reg[0][t + 2] - reg[0][t]) + 2.0f * (reg[1][t + 2] - reg[1][t])
       + (reg[2][t + 2] - reg[2][t]);
    sy = (reg[2][t] + 2.0f * reg[2][t + 1] + reg[2][t + 2])
       - (reg[0][t] + 2.0f * reg[0][t + 1] + reg[0][t + 2]);
    idn = reg[1][t + 1];
}

// --- k0a: pack w1 -> panel layout w1p + transposed w1T; w2 -> panel w2p -----
__global__ __launch_bounds__(256) void k0_convert(const float* __restrict__ w1,
                                                  const float* __restrict__ w2,
                                                  u16* __restrict__ w1p,
                                                  u16* __restrict__ w1T,
                                                  u16* __restrict__ w2p,
                                                  float* __restrict__ stats) {
    int g = blockIdx.x * 256 + threadIdx.x;
    if (g < NO * K1) {
        u16 v = f2bf(w1[g]);
        int o = g / K1, k = g - o * K1;
        int f = o >> 4, ks = k >> 5;
        int lane = (((k >> 3) & 3) << 4) | (o & 15);
        w1p[(size_t)(((f * 6 + ks) * 64 + lane) * 8 + (k & 7))] = v;
        w1T[(size_t)k * NO + o] = v;
    } else if (g < NO * K1 + NC * NO) {
        int i = g - NO * K1;
        int s = i / NO, o = i - s * NO;
        u16 v = f2bf(w2[i]);
        int wid = s >> 4, oc = o >> 6, ks2 = (o >> 5) & 1;
        int lane = (((o >> 3) & 3) << 4) | (s & 15);
        w2p[(size_t)((((wid * 8 + oc) * 2 + ks2) * 64 + lane) * 8 + (o & 7))] = v;
    } else if (g < NO * K1 + NC * NO + 256) {
        stats[g - NO * K1 - NC * NO] = 0.0f;
    }
}

// --- k0l: pack ln params into C-fragment panel order (coalesced reads) ------
__global__ __launch_bounds__(256) void k0_lncomb(const float* __restrict__ lnw,
                                                 const float* __restrict__ lnb,
                                                 u32* __restrict__ lnp) {
    int g = blockIdx.x * 256 + threadIdx.x;   // g = o*1600 + p
    int o = g / NHW, p = g - o * NHW;
    int bx = p / 80, pr = p - bx * 80;
    int mi = pr >> 4, l15 = pr & 15;
    int oc = o >> 6, ro = o & 63;
    int wid = ro >> 4, hi = (ro >> 2) & 3, r = ro & 3;
    int lane = (hi << 4) | l15;
    int outi = ((((bx * 8 + oc) * 4 + wid) * 5 + mi) << 8) + lane * 4 + r;
    lnp[outi] = ((u32)f2bf(lnb[g]) << 16) | f2bf(lnw[g]);
}

// --- k0g: G = w1^T w1 via MFMA (blocks 0..35); colw1 (block 36) -------------
__global__ __launch_bounds__(256) void k0_gram(const u16* __restrict__ w1T,
                                               float* __restrict__ G,
                                               float* __restrict__ colw1) {
    const int blk = blockIdx.x;
    const int tid = threadIdx.x;
    const int lane = tid & 63, wid = tid >> 6;
    const int q = lane >> 4, l15 = lane & 15;
    if (blk < 36) {
        int bj = blk / 6, bk = blk - bj * 6;
        int j0 = bj * 32 + (wid & 1) * 16, k0 = bk * 32 + (wid >> 1) * 16;
        f32x4 acc = {0.f, 0.f, 0.f, 0.f};
#pragma unroll
        for (int ks = 0; ks < 16; ++ks) {
            bf16x8 a  = ldfrag(&w1T[(size_t)(j0 + l15) * NO + ks * 32 + q * 8]);
            bf16x8 bb = ldfrag(&w1T[(size_t)(k0 + l15) * NO + ks * 32 + q * 8]);
            acc = mfma16(a, bb, acc);
        }
#pragma unroll
        for (int r = 0; r < 4; ++r)
            G[(size_t)(j0 + q * 4 + r) * K1 + k0 + l15] = acc[r];
    } else if (tid < K1) {
        float s = 0.f;
        for (int i = 0; i < NO / 8; ++i) {
            ushort8 v = *(const ushort8*)&w1T[(size_t)tid * NO + i * 8];
#pragma unroll
            for (int j = 0; j < 8; ++j) s += bf2f(v[j]);
        }
        colw1[tid] = s;
    }
}

// --- k2: per-sample LN stats via Gram MFMA — strip-parallel, fi-outer -------
// (frozen from v10: no min-waves bound -> no spill; fi-outer keeps acc[6]
// live; 2560 blocks; LDS 40144 B)
__global__ __launch_bounds__(256) void k2_stats(const float* __restrict__ state,
                                                const float* __restrict__ G,
                                                const float* __restrict__ colw1,
                                                float* __restrict__ stats) {
    const int bx = blockIdx.x;                    // 0..19 strip
    const int b  = blockIdx.y;
    const int h0 = bx * 2;
    const int tid = threadIdx.x;
    const int lane = tid & 63, wid = tid >> 6;
    const int q = lane >> 4, l15 = lane & 15;
    const int j0 = (wid & 1) * 96, j1 = (wid >> 1) * 96, jo = wid * 48;

    __shared__ __align__(16) u16 Pt[193 * 104];   // 40144 B
    __shared__ float red[8];

    for (int i = tid; i < 193 * 104 / 8; i += 256) ((u32x4*)Pt)[i] = (u32x4){0,0,0,0};
    __syncthreads();
    if (tid < 80) Pt[192 * 104 + tid] = 0x3F80u;  // ones row (bf16 1.0)

    // perception: 2 rows, identical code to k4 (bitwise-identical bf16 P)
    {
        const int c = tid >> 2, wq = tid & 3;
        const float* base = state + ((size_t)b * NC + c) * NHW;
        for (int rr = 0; rr < 2; ++rr) {
            float reg[3][12];
            load_halo(base, h0 + rr, wq, reg);
#pragma unroll
            for (int t = 0; t < 10; ++t) {
                float sx, sy, idn; sobel_px(reg, t, sx, sy, idn);
                int px = rr * 40 + wq * 10 + t;
                Pt[(3 * c + 0) * 104 + px] = f2bf(sx);
                Pt[(3 * c + 1) * 104 + px] = f2bf(sy);
                Pt[(3 * c + 2) * 104 + px] = f2bf(idn);
            }
        }
    }
    __syncthreads();

    float ssq = 0.f;
#pragma unroll 1
    for (int fi = 0; fi < 6; ++fi) {
        f32x4 acc[6];
#pragma unroll
        for (int j = 0; j < 6; ++j) { f32x4 z = {0.f,0.f,0.f,0.f}; acc[j] = z; }
#pragma unroll
        for (int ks = 0; ks < 3; ++ks) {
            bf16x8 av = ldfrag(&Pt[(j0 + fi * 16 + l15) * 104 + ks * 32 + q * 8]);
#pragma unroll
            for (int fj = 0; fj < 6; ++fj) {
                bf16x8 bv = ldfrag(&Pt[(j1 + fj * 16 + l15) * 104 + ks * 32 + q * 8]);
                acc[fj] = mfma16(av, bv, acc[fj]);
            }
        }
#pragma unroll
        for (int fj = 0; fj < 6; ++fj) {
            f32x4 gv = *(const f32x4*)&G[(size_t)(j1 + fj * 16 + l15) * K1
                                         + j0 + fi * 16 + q * 4];
#pragma unroll
            for (int r = 0; r < 4; ++r) ssq += acc[fj][r] * gv[r];
        }
    }

    // ones-row pass: colsums of wid's 48-col slice (every D-row = colsum)
    f32x4 accO[3];
#pragma unroll
    for (int j = 0; j < 3; ++j) { f32x4 z = {0.f,0.f,0.f,0.f}; accO[j] = z; }
#pragma unroll
    for (int ks = 0; ks < 3; ++ks) {
        bf16x8 ao = ldfrag(&Pt[192 * 104 + ks * 32 + q * 8]);   // broadcast row
#pragma unroll
        for (int fj = 0; fj < 3; ++fj) {
            bf16x8 bo = ldfrag(&Pt[(jo + fj * 16 + l15) * 104 + ks * 32 + q * 8]);
            accO[fj] = mfma16(ao, bo, accO[fj]);
        }
    }
    float sm = 0.f;
    if (q == 0) {
#pragma unroll
        for (int fj = 0; fj < 3; ++fj)
            sm += accO[fj][0] * colw1[jo + fj * 16 + l15];
    }

#pragma unroll
    for (int off = 32; off > 0; off >>= 1) {
        ssq += __shfl_down(ssq, off);
        sm  += __shfl_down(sm, off);
    }
    if (lane == 0) { red[wid] = ssq; red[4 + wid] = sm; }
    __syncthreads();
    if (tid == 0) {
        atomicAdd(&stats[b * 2],     red[4] + red[5] + red[6] + red[7]);
        atomicAdd(&stats[b * 2 + 1], red[0] + red[1] + red[2] + red[3]);
    }
}

// --- k4: fused percept -> GEMM1 -> LN/ReLU -> GEMM2 -> gate+residual --------
// v11: lb(256,3) (LDS caps occupancy at 3 blk/CU anyway; 170-reg cap gives
// prefetch headroom); w1 A-frags software-pipelined one oc ahead; LN finalize
// (old k3) inlined — reads stats[] directly.
__global__ __launch_bounds__(256, 3) void k4_fused(const float* __restrict__ state,
                                                   const u16* __restrict__ w1p,
                                                   const u16* __restrict__ w2p,
                                                   const u32* __restrict__ lnp,
                                                   const int* __restrict__ mask,
                                                   const float* __restrict__ stats,
                                                   float* __restrict__ out) {
    const int bx = blockIdx.x;                    // 0..19
    const int b  = blockIdx.y;
    const int p0 = bx * 80, h0 = bx * 2;
    const int tid = threadIdx.x;
    const int lane = tid & 63, wid = tid >> 6;
    const int q = lane >> 4, l15 = lane & 15;

    __shared__ __align__(16) u16 Pt[80 * 192];    // 30720 B
    __shared__ __align__(16) u16 Ys[80 * 64];     // 10240 B [p][o-chunk] swizzled

    // LN finalize inlined (was k3): same arithmetic, broadcast loads
    const float s_sum = stats[2 * b], s_sq = stats[2 * b + 1];
    const float inv = 1.0f / LN_N;
    const float mu = s_sum * inv;
    const float var = s_sq * inv - mu * mu;
    const float rs = rsqrtf(var + 1e-5f);
    const float murs = mu * rs;

    // perception -> Pt [p][192], group-of-8 XOR swizzle on 16B units
    {
        const int c = tid >> 2, wq = tid & 3;
        const float* base = state + ((size_t)b * NC + c) * NHW;
        for (int rr = 0; rr < 2; ++rr) {
            float reg[3][12];
            load_halo(base, h0 + rr, wq, reg);
#pragma unroll
            for (int t = 0; t < 10; ++t) {
                float sx, sy, idn; sobel_px(reg, t, sx, sy, idn);
                int px = rr * 40 + wq * 10 + t;
                int k = 3 * c;
#pragma unroll
                for (int i = 0; i < 3; ++i) {
                    int kk = k + i, u = kk >> 3;
                    int elem = px * 192 + (((u & 0x18) | ((u ^ px) & 7)) << 3) + (kk & 7);
                    Pt[elem] = f2bf(i == 0 ? sx : (i == 1 ? sy : idn));
                }
            }
        }
    }
    // gate in VGPRs: g5[mi] for p = p0 + mi*16 + l15
    float g5[5];
    {
        const float* st3 = state + ((size_t)b * NC + 3) * NHW;
#pragma unroll
        for (int mi = 0; mi < 5; ++mi) {
            int p = p0 + mi * 16 + l15;
            int h = p / 40, w = p - h * 40;
            float mx = -1e30f;
#pragma unroll
            for (int dh = -1; dh <= 1; ++dh) {
                int hh = h + dh;
                if ((unsigned)hh < 40u)
#pragma unroll
                    for (int dw = -1; dw <= 1; ++dw) {
                        int wc = w + dw;
                        if ((unsigned)wc < 40u) mx = fmaxf(mx, st3[hh * 40 + wc]);
                    }
            }
            g5[mi] = (mx > 0.1f && mask[p] != 0) ? 1.0f : 0.0f;
        }
    }

    // ---- block-constant LDS addressing (hoisted out of the oc loop) --------
    int pB0[5], pB1[5], yR0[5], yR1[5], yW[5];
    {
        const int q8 = q << 3;
        const int wu = wid * 2 + (q >> 1);
#pragma unroll
        for (int mi = 0; mi < 5; ++mi) {
            int r  = mi * 16 + l15;
            int xr = (r & 7) << 3;
            pB0[mi] = r * 192 + (q8 ^ xr);
            pB1[mi] = r * 192 + ((q8 + 32) ^ xr);
            int px = r & 7;
            yR0[mi] = r * 64 + ((q ^ px) << 3);
            yR1[mi] = r * 64 + (((q + 4) ^ px) << 3);
            yW[mi]  = r * 64 + ((wu ^ px) << 3) + (q & 1) * 4;
        }
    }

    // ---- w1 A-frag software pipeline: preload oc=0 ----
    bf16x8 a_cur[6];
    {
        const u16* w1base0 = w1p + ((size_t)(0 * 4 + wid) * 6) * 512 + lane * 8;
#pragma unroll
        for (int ks = 0; ks < 6; ++ks) a_cur[ks] = ldfrag(w1base0 + ks * 512);
    }
    __syncthreads();

    f32x4 acc2[5];
#pragma unroll
    for (int i = 0; i < 5; ++i) { f32x4 z = {0.f,0.f,0.f,0.f}; acc2[i] = z; }

    for (int oc = 0; oc < 8; ++oc) {
        // prefetch ln C-fragments (panel layout: lane*16B, coalesced)
        u32x4 lv[5];
        {
            const u32* lb = lnp + ((((size_t)bx * 8 + oc) * 4 + wid) * 5) * 256 + lane * 4;
#pragma unroll
            for (int mi = 0; mi < 5; ++mi)
                lv[mi] = *(const u32x4*)(lb + mi * 256);
        }
        // prefetch w2 A-frags for this chunk (panel layout, coalesced)
        const u16* w2base = w2p + ((size_t)(wid * 8 + oc) * 2) * 512 + lane * 8;
        bf16x8 aw0 = ldfrag(w2base);
        bf16x8 aw1 = ldfrag(w2base + 512);

        // ---- GEMM1: D[o][p], wave o-tile 16; prefetch next oc's A-frags ----
        const u16* w1next = w1p + ((size_t)((((oc + 1) & 7) * 4 + wid) * 6)) * 512
                          + lane * 8;
        f32x4 acc1[5];
#pragma unroll
        for (int i = 0; i < 5; ++i) { f32x4 z = {0.f,0.f,0.f,0.f}; acc1[i] = z; }
#pragma unroll
        for (int ks = 0; ks < 6; ++ks) {
            bf16x8 a = a_cur[ks];
            a_cur[ks] = ldfrag(w1next + ks * 512);   // depth-1 pipeline
#pragma unroll
            for (int mi = 0; mi < 5; ++mi) {
                int off = ((ks & 1) ? pB1[mi] : pB0[mi]) + (ks >> 1) * 64;
                acc1[mi] = mfma16(a, ldfrag(&Pt[off]), acc1[mi]);
            }
        }
        // ---- transform: Y = relu((x-mu)*rs*lnw + lnb) -> Ys (b64 swizzled) ----
#pragma unroll
        for (int mi = 0; mi < 5; ++mi) {
            u16x4 yv;
#pragma unroll
            for (int r = 0; r < 4; ++r) {
                u32 cc = lv[mi][r];
                float t = fmaf(acc1[mi][r], rs, -murs);
                float y = fmaxf(fmaf(t, bflo(cc), bfhi(cc)), 0.0f);
                yv[r] = f2bf(y);
            }
            *(u16x4*)&Ys[yW[mi]] = yv;
        }
        __syncthreads();
        // ---- GEMM2 partial: D[s][p] += w2[s][o64] * Ys[o64][p] ----
#pragma unroll
        for (int ks2 = 0; ks2 < 2; ++ks2) {
            bf16x8 aw = ks2 ? aw1 : aw0;
#pragma unroll
            for (int mi = 0; mi < 5; ++mi) {
                int off = ks2 ? yR1[mi] : yR0[mi];
                acc2[mi] = mfma16(aw, ldfrag(&Ys[off]), acc2[mi]);
            }
        }
        __syncthreads();                          // Ys reads done before rewrite
    }

    // ---- epilogue: direct gated residual stores ----
#pragma unroll
    for (int mi = 0; mi < 5; ++mi) {
        int p = p0 + mi * 16 + l15;
        float g = g5[mi];
#pragma unroll
        for (int r = 0; r < 4; ++r) {
            int s = wid * 16 + q * 4 + r;
            size_t idx = ((size_t)b * NC + s) * NHW + p;
            out[idx] = state[idx] + g * acc2[mi][r];
        }
    }
}

// ---------------------------------------------------------------------------
extern "C" void kernel_launch(void* const* d_in, const int* in_sizes, int n_in,
                              void* d_out, int out_size, void* d_ws, size_t ws_size,
                              hipStream_t stream) {
    const float* state = (const float*)d_in[0];
    const float* w1    = (const float*)d_in[1];
    const float* lnw   = (const float*)d_in[2];
    const float* lnb   = (const float*)d_in[3];
    const float* w2    = (const float*)d_in[4];
    const int*   mask  = (const int*)d_in[5];
    float* out = (float*)d_out;

    char* ws = (char*)d_ws;
    // workspace layout (total ~3.89 MB):
    u16*    w1p   = (u16*)(ws + 0ull);          //   196,608  panel layout
    u16*    w2p   = (u16*)(ws + 196608ull);     //    65,536  panel layout
    u32*    lnp   = (u32*)(ws + 262144ull);     // 3,276,800  panel (lnb|lnw)
    u16*    w1T   = (u16*)(ws + 3538944ull);    //   196,608  [k][o]
    float*  G     = (float*)(ws + 3735552ull);  //   147,456  w1^T w1
    float*  colw1 = (float*)(ws + 3883008ull);  //       768
    float*  stats = (float*)(ws + 3883776ull);  //     1,024  (sum,sumsq)*128
    // musig slot unused in v11 (k3 folded into k4)

    k0_convert <<<513, 256, 0, stream>>>(w1, w2, w1p, w1T, w2p, stats);
    k0_lncomb  <<<3200, 256, 0, stream>>>(lnw, lnb, lnp);
    k0_gram    <<<37, 256, 0, stream>>>(w1T, G, colw1);
    k2_stats   <<<dim3(20, 128), 256, 0, stream>>>(state, G, colw1, stats);
    k4_fused   <<<dim3(20, 128), 256, 0, stream>>>(state, w1p, w2p, lnp,
                                                   mask, stats, out);
}